// Round 1
// baseline (220.895 us; speedup 1.0000x reference)
//
#include <hip/hip_runtime.h>
#include <hip/hip_bf16.h>
#include <cstdint>

#define IN_CH 512
#define OUT_CH 512
#define STYLE_DIM 512
#define BATCH 8
#define HW 64

typedef __bf16 bf16x8 __attribute__((ext_vector_type(8)));
typedef float f32x16 __attribute__((ext_vector_type(16)));

__device__ __forceinline__ void gload_lds16(const void* g, void* l) {
  __builtin_amdgcn_global_load_lds(
      (const __attribute__((address_space(1))) unsigned int*)g,
      (__attribute__((address_space(3))) unsigned int*)l,
      16, 0, 0);
}

#define WAITV(N) asm volatile("s_waitcnt vmcnt(" #N ")" ::: "memory")
#define BARRIER() do { asm volatile("" ::: "memory"); __builtin_amdgcn_s_barrier(); asm volatile("" ::: "memory"); } while (0)

// ---------------- prepass 1: s[b][ic] = style @ (modw*lin_scale)^T + bias ----------------
__global__ void k_style(const float* __restrict__ style, const float* __restrict__ modw,
                        const float* __restrict__ modb, float* __restrict__ s_out) {
  const int b = blockIdx.x;        // 8 blocks
  const int ic = threadIdx.x;      // 512 threads
  __shared__ float st[STYLE_DIM];
  st[ic] = style[b * STYLE_DIM + ic];
  __syncthreads();
  const float* wr = modw + (size_t)ic * STYLE_DIM;
  float acc = 0.f;
  #pragma unroll 8
  for (int d = 0; d < STYLE_DIM; ++d) acc += st[d] * wr[d];
  const float LIN_SCALE = 0.04419417382415922f;  // 1/sqrt(512)
  s_out[b * IN_CH + ic] = acc * LIN_SCALE + modb[ic];
}

// ---------------- prepass 2: wsq[oc][ic] = sum_t W^2 ; Wb[t][oc][ic^swz] = bf16(W) ------
__global__ void k_wprep(const float* __restrict__ w, float* __restrict__ wsq,
                        __bf16* __restrict__ wb) {
  const int idx = blockIdx.x * 256 + threadIdx.x;  // 262144
  const int oc = idx >> 9, ic = idx & 511;
  const float* p = w + ((size_t)oc * IN_CH + ic) * 9;
  const int icw = ic ^ ((oc & 7) << 3);
  float sum = 0.f;
  #pragma unroll
  for (int t = 0; t < 9; ++t) {
    float v = p[t];
    sum += v * v;
    wb[((size_t)(t * OUT_CH) + oc) * IN_CH + icw] = (__bf16)v;
  }
  wsq[oc * IN_CH + ic] = sum;
}

// ---------------- prepass 3: scale[b][oc] = rsqrt(cs^2*sum(s^2*wsq)+eps)*cs --------------
__global__ void k_demod(const float* __restrict__ s, const float* __restrict__ wsq,
                        float* __restrict__ scale) {
  const int idx = blockIdx.x * 256 + threadIdx.x;  // 4096
  const int oc = idx >> 3, b = idx & 7;
  const float* sr = s + b * IN_CH;
  const float* wr = wsq + (size_t)oc * IN_CH;
  float acc = 0.f;
  #pragma unroll 8
  for (int i = 0; i < IN_CH; ++i) {
    float sv = sr[i];
    acc += sv * sv * wr[i];
  }
  const float CS = 0.014731391274719732f;   // 1/sqrt(4608)
  const float CS2 = 1.0f / 4608.0f;
  scale[b * OUT_CH + oc] = rsqrtf(acc * CS2 + 1e-8f) * CS;
}

// ---------------- prepass 4: xg[b][y][x][ic^swz] = bf16(x[b][ic][y][x] * s[b][ic]) -------
__global__ void k_xprep(const float* __restrict__ x, const float* __restrict__ s,
                        __bf16* __restrict__ xg) {
  const int blk = blockIdx.x;      // 8*64
  const int y = blk & 63;
  const int b = blk >> 6;
  const int xcol = threadIdx.x >> 3;   // 0..63
  const int u = threadIdx.x & 7;       // 0..7
  const float* sr = s + b * IN_CH;
  const int key = (xcol + 1) & 7;
  __bf16* obase = xg + (((size_t)(b * HW + y) * HW + xcol) * IN_CH);
  #pragma unroll
  for (int it = 0; it < 8; ++it) {
    const int ug = it * 8 + u;   // ic group 0..63
    bf16x8 pk;
    #pragma unroll
    for (int j = 0; j < 8; ++j) {
      const int ic = ug * 8 + j;
      float v = x[(((size_t)(b * IN_CH) + ic) * HW + y) * HW + xcol] * sr[ic];
      pk[j] = (__bf16)v;
    }
    *(bf16x8*)(obase + (size_t)(ug ^ key) * 8) = pk;
  }
}

// ---------------- main: implicit-GEMM conv, bf16 MFMA 32x32x16 ---------------------------
// block tile: 256 oc x 256 pixels (4 image rows), 8 waves (2M x 4N), wave tile 128x64
__global__ __launch_bounds__(512, 2) void k_conv(
    const __bf16* __restrict__ Wg,   // [9][512][512] ic pre-swizzled by (oc&7)
    const __bf16* __restrict__ Xg,   // [8][64][64][512] ic pre-swizzled by ((x+1)&7)
    const float* __restrict__ scale, // [8][512] = demod*cs
    float* __restrict__ out)         // [8][512][64][64]
{
  __shared__ __attribute__((aligned(16))) __bf16 Xs[6 * 66 * 64];   // 50688 B, halos stay 0
  __shared__ __attribute__((aligned(16))) __bf16 Wl[2][256 * 64];   // 65536 B double-buffered

  const int tid = threadIdx.x;
  const int lane = tid & 63;
  const int wid = tid >> 6;
  const int wm = wid >> 2;      // 0..1  (oc half)
  const int wn = wid & 3;       // 0..3  (image row within tile)
  const int ln31 = lane & 31;
  const int laneK = lane >> 5;  // 0/1

  const int bid = blockIdx.x;
  const int octile = bid & 1;
  const int ptile = (bid >> 1) & 15;
  const int b = bid >> 5;
  const int oc0 = octile * 256;
  const int r0 = ptile * 4;

  // zero X LDS once (provides conv zero-padding via halo rows/cols)
  for (int i = tid; i < 6 * 66 * 64; i += 512) Xs[i] = (__bf16)0.0f;
  __syncthreads();

  const int scol = tid >> 3;   // 0..63
  const int su = tid & 7;      // 0..7

  auto stage_x = [&](int chunk) {   // 6 global_load_lds per thread (edge rows skipped -> stay 0)
    const int ic0 = chunk * 64;
    #pragma unroll
    for (int row = 0; row < 6; ++row) {
      const int y = r0 - 1 + row;
      if (y >= 0 && y < HW) {
        gload_lds16(Xg + (((size_t)(b * HW + y) * HW + scol) * IN_CH + ic0 + su * 8),
                    &Xs[(row * 66 + scol + 1) * 64 + su * 8]);
      }
    }
  };
  auto stage_w = [&](int chunk, int tap, int bsel) {  // 4 global_load_lds per thread
    const int ic0 = chunk * 64;
    #pragma unroll
    for (int i = 0; i < 4; ++i) {
      const int sidx = tid + 512 * i;
      const int oc = sidx >> 3, u = sidx & 7;
      gload_lds16(Wg + (((size_t)(tap * OUT_CH) + oc0 + oc) * IN_CH + ic0 + u * 8),
                  &Wl[bsel][oc * 64 + u * 8]);
    }
  };

  f32x16 acc[4][2] = {};

  stage_x(0);
  stage_w(0, 0, 0);
  int cur = 0;

  const int akey8 = (ln31 & 7) * 8;   // A-read swizzle key (oc&7 == ln31&7)
  const int kb = laneK * 8;

  for (int chunk = 0; chunk < 8; ++chunk) {
    for (int tap = 0; tap < 9; ++tap) {
      if (tap < 8) {
        stage_w(chunk, tap + 1, cur ^ 1);  // prefetch next tap's W
        WAITV(4);                          // drain everything except the 4 just issued
      } else {
        WAITV(0);
      }
      BARRIER();
      {
        const int dy = tap / 3 - 1, dx = tap % 3 - 1;
        const int xrow = wn + 1 + dy;              // 0..5
        const int col0 = ln31 + 1 + dx;            // LDS col for nf=0 (halo col 0/65 = zeros)
        const int bkey8 = (col0 & 7) * 8;          // same key for col0+32
        const __bf16* __restrict__ xb0 = &Xs[(xrow * 66 + col0) * 64];
        const __bf16* __restrict__ xb1 = xb0 + 32 * 64;
        const __bf16* __restrict__ wbase = &Wl[cur][(128 * wm + ln31) * 64];
        #pragma unroll
        for (int ks = 0; ks < 4; ++ks) {
          const int ael = (ks * 16 + kb) ^ akey8;
          const int bel = (ks * 16 + kb) ^ bkey8;
          bf16x8 bv0 = *(const bf16x8*)(xb0 + bel);
          bf16x8 bv1 = *(const bf16x8*)(xb1 + bel);
          #pragma unroll
          for (int mf = 0; mf < 4; ++mf) {
            bf16x8 av = *(const bf16x8*)(wbase + mf * 2048 + ael);
            acc[mf][0] = __builtin_amdgcn_mfma_f32_32x32x16_bf16(av, bv0, acc[mf][0], 0, 0, 0);
            acc[mf][1] = __builtin_amdgcn_mfma_f32_32x32x16_bf16(av, bv1, acc[mf][1], 0, 0, 0);
          }
        }
      }
      cur ^= 1;
      BARRIER();   // all waves done reading before the buffer is restaged
    }
    if (chunk < 7) {            // X single-buffered: stage after last tap's compute
      stage_x(chunk + 1);
      stage_w(chunk + 1, 0, cur);
    }
  }

  // epilogue: out = acc * (demod*cs), NCHW
  const int y = r0 + wn;
  #pragma unroll
  for (int mf = 0; mf < 4; ++mf) {
    #pragma unroll
    for (int reg = 0; reg < 16; ++reg) {
      const int rowid = (reg & 3) + 8 * (reg >> 2) + 4 * laneK;
      const int oc = oc0 + 128 * wm + 32 * mf + rowid;
      const float sc = scale[b * OUT_CH + oc];
      float* op = out + (((size_t)(b * OUT_CH + oc) * HW + y) * HW) + ln31;
      op[0] = acc[mf][0][reg] * sc;
      op[32] = acc[mf][1][reg] * sc;
    }
  }
}

// ---------------- launcher ---------------------------------------------------------------
extern "C" void kernel_launch(void* const* d_in, const int* in_sizes, int n_in,
                              void* d_out, int out_size, void* d_ws, size_t ws_size,
                              hipStream_t stream) {
  const float* x      = (const float*)d_in[0];  // 8*512*64*64
  const float* style  = (const float*)d_in[1];  // 8*512
  const float* weight = (const float*)d_in[2];  // 512*512*3*3
  const float* modw   = (const float*)d_in[3];  // 512*512
  const float* modb   = (const float*)d_in[4];  // 512
  float* out = (float*)d_out;

  char* ws = (char*)d_ws;
  float*  s_buf = (float*)(ws + 0);                       // 16 KB
  float*  scale = (float*)(ws + 16384);                   // 16 KB
  float*  wsq   = (float*)(ws + 32768);                   // 1 MB
  __bf16* wb    = (__bf16*)(ws + 32768 + 1048576);        // 9*512*512*2 = 4.718 MB
  __bf16* xg    = (__bf16*)(ws + 32768 + 1048576 + 9 * OUT_CH * IN_CH * 2);  // 33.55 MB

  k_style<<<8, 512, 0, stream>>>(style, modw, modb, s_buf);
  k_wprep<<<1024, 256, 0, stream>>>(weight, wsq, wb);
  k_demod<<<16, 256, 0, stream>>>(s_buf, wsq, scale);
  k_xprep<<<BATCH * HW, 512, 0, stream>>>(x, s_buf, xg);
  k_conv<<<256, 512, 0, stream>>>(wb, xg, scale, out);
}

// Round 2
// 202.470 us; speedup vs baseline: 1.0910x; 1.0910x over previous
//
#include <hip/hip_runtime.h>
#include <hip/hip_bf16.h>
#include <cstdint>

#define IN_CH 512
#define OUT_CH 512
#define STYLE_DIM 512
#define BATCH 8
#define HW 64

typedef __bf16 bf16x8 __attribute__((ext_vector_type(8)));
typedef float f32x16 __attribute__((ext_vector_type(16)));

__device__ __forceinline__ void gload_lds16(const void* g, void* l) {
  __builtin_amdgcn_global_load_lds(
      (const __attribute__((address_space(1))) unsigned int*)g,
      (__attribute__((address_space(3))) unsigned int*)l,
      16, 0, 0);
}

#define WAITV(N) asm volatile("s_waitcnt vmcnt(" #N ")" ::: "memory")
#define LGKM0()  do { asm volatile("s_waitcnt lgkmcnt(0)" ::: "memory"); \
                      __builtin_amdgcn_sched_barrier(0); } while (0)
#define BARRIER() do { asm volatile("" ::: "memory"); __builtin_amdgcn_s_barrier(); \
                       asm volatile("" ::: "memory"); } while (0)

// ---------------- prepass 1: s[b][ic] = style @ (modw*lin_scale)^T + bias ----------------
// 128 blocks x 256 thr; block = 4 ics, all 8 batches; modw read once, coalesced
__global__ void k_style(const float* __restrict__ style, const float* __restrict__ modw,
                        const float* __restrict__ modb, float* __restrict__ s_out) {
  __shared__ float st[BATCH * STYLE_DIM];
  const int tid = threadIdx.x;
  for (int i = tid; i < BATCH * STYLE_DIM; i += 256) st[i] = style[i];
  __syncthreads();
  const int ic = blockIdx.x * 4 + (tid >> 6);
  const int l = tid & 63;
  const float* mr = modw + (size_t)ic * STYLE_DIM + l * 8;
  float m[8];
  #pragma unroll
  for (int j = 0; j < 8; ++j) m[j] = mr[j];
  float accs[8];
  #pragma unroll
  for (int b = 0; b < 8; ++b) {
    const float* sb = st + b * STYLE_DIM + l * 8;
    float a = 0.f;
    #pragma unroll
    for (int j = 0; j < 8; ++j) a += m[j] * sb[j];
    accs[b] = a;
  }
  #pragma unroll
  for (int off = 32; off; off >>= 1) {
    #pragma unroll
    for (int b = 0; b < 8; ++b) accs[b] += __shfl_down(accs[b], off, 64);
  }
  if (l == 0) {
    #pragma unroll
    for (int b = 0; b < 8; ++b)
      s_out[b * IN_CH + ic] = accs[b] * 0.04419417382415922f + modb[ic];
  }
}

// ---------------- prepass 2: wsq[oc][ic] = sum_t W^2 ; Wb[t][oc][ic^swz] = bf16(W) ------
__global__ void k_wprep(const float* __restrict__ w, float* __restrict__ wsq,
                        __bf16* __restrict__ wb) {
  const int idx = blockIdx.x * 256 + threadIdx.x;  // 262144
  const int oc = idx >> 9, ic = idx & 511;
  const float* p = w + ((size_t)oc * IN_CH + ic) * 9;
  const int icw = ic ^ ((oc & 7) << 3);
  float sum = 0.f;
  #pragma unroll
  for (int t = 0; t < 9; ++t) {
    float v = p[t];
    sum += v * v;
    wb[((size_t)(t * OUT_CH) + oc) * IN_CH + icw] = (__bf16)v;
  }
  wsq[oc * IN_CH + ic] = sum;
}

// ---------------- prepass 3: scale[b][oc] = rsqrt(cs^2*sum(s^2*wsq)+eps)*cs --------------
// 512 blocks x 64 thr; wsq row read once
__global__ void k_demod(const float* __restrict__ s, const float* __restrict__ wsq,
                        float* __restrict__ scale) {
  const int oc = blockIdx.x;
  const int l = threadIdx.x;
  const float* wr = wsq + (size_t)oc * IN_CH + l * 8;
  float w8[8];
  #pragma unroll
  for (int j = 0; j < 8; ++j) w8[j] = wr[j];
  #pragma unroll
  for (int b = 0; b < 8; ++b) {
    const float* sb = s + b * IN_CH + l * 8;
    float acc = 0.f;
    #pragma unroll
    for (int j = 0; j < 8; ++j) { float sv = sb[j]; acc += sv * sv * w8[j]; }
    #pragma unroll
    for (int off = 32; off; off >>= 1) acc += __shfl_down(acc, off, 64);
    if (l == 0)
      scale[b * OUT_CH + oc] =
          rsqrtf(acc * (1.0f / 4608.0f) + 1e-8f) * 0.014731391274719732f;
  }
}

// ---------------- prepass 4: xg[b][ug][y][x][8] = bf16(x * s), ug = ic/8 -----------------
// fully coalesced both sides; swizzle handled by conv's per-lane global source address
__global__ void k_xprep(const float* __restrict__ x, const float* __restrict__ s,
                        __bf16* __restrict__ xg) {
  const int b = blockIdx.x >> 6, y = blockIdx.x & 63;   // 512 blocks
  const int w = threadIdx.x >> 6, lane = threadIdx.x & 63;
  const float* sr = s + b * IN_CH;
  #pragma unroll
  for (int it = 0; it < 8; ++it) {
    const int ug = it * 8 + w;
    bf16x8 pk;
    #pragma unroll
    for (int j = 0; j < 8; ++j) {
      const int ic = ug * 8 + j;
      pk[j] = (__bf16)(x[(((size_t)(b * IN_CH) + ic) * HW + y) * HW + lane] * sr[ic]);
    }
    *(bf16x8*)(xg + ((((size_t)(b * 64 + ug) * HW + y) * HW + lane) * 8)) = pk;
  }
}

// ---------------- main: implicit-GEMM conv, 2-phase/tap counted-vmcnt schedule -----------
// block 256 oc x 256 px, 8 waves (2M x 4N), wave tile 128x64, W triple-buffered 2-deep
__global__ __launch_bounds__(512, 2) void k_conv(
    const __bf16* __restrict__ Wg,   // [9][512][512] ic pre-swizzled by (oc&7)
    const __bf16* __restrict__ Xg,   // [8][64 ug][64 y][64 x][8] (no swizzle)
    const float* __restrict__ scale, // [8][512] = demod*cs
    float* __restrict__ out)         // [8][512][64][64]
{
  __shared__ __attribute__((aligned(16))) __bf16 Xs[6 * 66 * 64];   // 50688 B
  __shared__ __attribute__((aligned(16))) __bf16 Wl[3][256 * 64];   // 98304 B

  const int tid = threadIdx.x;
  const int lane = tid & 63;
  const int wid = tid >> 6;
  const int wm = wid >> 2;
  const int wn = wid & 3;
  const int ln31 = lane & 31;
  const int laneK = lane >> 5;

  // XCD-chunked block swizzle: XCD x gets all 32 blocks of batch x
  const int bid0 = blockIdx.x;
  const int bid = (bid0 & 7) * 32 + (bid0 >> 3);
  const int octile = bid & 1;
  const int ptile = (bid >> 1) & 15;
  const int b = bid >> 5;
  const int oc0 = octile * 256;
  const int r0 = ptile * 4;

  // zero X LDS once (halo rows/cols provide conv zero-padding; never rewritten)
  {
    float4 z = {0.f, 0.f, 0.f, 0.f};
    float4* p = (float4*)Xs;
    for (int i = tid; i < 6 * 66 * 64 * 2 / 16; i += 512) p[i] = z;
  }
  __syncthreads();

  const int scol = tid >> 3;   // 0..63
  const int su = tid & 7;      // 0..7

  auto stage_x = [&](int chunk) {   // 6 gload per thread; dest = uniform + lane*16
    const int ug = chunk * 8 + (su ^ ((scol + 1) & 7));   // swizzle via global src addr
    #pragma unroll
    for (int row = 0; row < 6; ++row) {
      const int y = r0 - 1 + row;
      if (y >= 0 && y < HW) {
        gload_lds16(Xg + ((((size_t)(b * 64 + ug) * HW + y) * HW + scol) * 8),
                    &Xs[(row * 66 + scol + 1) * 64 + su * 8]);
      }
    }
  };
  auto stage_w = [&](int chunk, int tap, int bsel) {  // 4 gload per thread
    const int ic0 = chunk * 64;
    #pragma unroll
    for (int i = 0; i < 4; ++i) {
      const int sidx = tid + 512 * i;
      const int oc = sidx >> 3, u = sidx & 7;
      gload_lds16(Wg + (((size_t)(tap * OUT_CH) + oc0 + oc) * IN_CH + ic0 + u * 8),
                  &Wl[bsel][oc * 64 + u * 8]);
    }
  };

  f32x16 acc[4][2] = {};

  const int akey8 = (ln31 & 7) * 8;
  const int kb = laneK * 8;
  int ael[4];
  #pragma unroll
  for (int ks = 0; ks < 4; ++ks) ael[ks] = (ks * 16 + kb) ^ akey8;

  // prologue: queue = X0(6), W0(4), W1(4)
  stage_x(0);
  stage_w(0, 0, 0);
  stage_w(0, 1, 1);
  WAITV(4);      // X0 + W0 landed, W1 in flight
  BARRIER();

  int tap = 0, chunk = 0, buf = 0;

  for (int s = 0; s < 72; ++s) {
    const int dy = tap / 3 - 1, dx = tap % 3 - 1;
    const int xrow = wn + 1 + dy;
    const int col0 = ln31 + 1 + dx;
    const int bkey8 = (col0 & 7) * 8;
    const __bf16* __restrict__ xb0 = &Xs[(xrow * 66 + col0) * 64];
    const __bf16* __restrict__ wbase = &Wl[buf][(128 * wm + ln31) * 64];

    // ================= phase A (ks 0,1) =================
    if (s + 2 < 72) {                       // prefetch W(s+2) into buf (buf+2)%3
      int t2 = tap + 2, c2 = chunk, b2 = buf + 2;
      if (t2 >= 9) { t2 -= 9; ++c2; }
      if (b2 >= 3) b2 -= 3;
      stage_w(c2, t2, b2);
    }
    if (tap == 0 && s > 0) {                // chunk boundary: publish new Xs
      WAITV(4);                             // queue: W(s+1),X(6),W(s+2) -> drain X; W(s+2) stays
      BARRIER();
    }
    {
      bf16x8 av[2][4], bv[2][2];
      #pragma unroll
      for (int kk = 0; kk < 2; ++kk) {
        const int bel = ((kk * 16 + kb) ^ bkey8);
        bv[kk][0] = *(const bf16x8*)(xb0 + bel);
        bv[kk][1] = *(const bf16x8*)(xb0 + 32 * 64 + bel);
        #pragma unroll
        for (int mf = 0; mf < 4; ++mf)
          av[kk][mf] = *(const bf16x8*)(wbase + mf * 2048 + ael[kk]);
      }
      BARRIER();
      LGKM0();
      __builtin_amdgcn_s_setprio(1);
      #pragma unroll
      for (int kk = 0; kk < 2; ++kk) {
        #pragma unroll
        for (int mf = 0; mf < 4; ++mf) {
          acc[mf][0] = __builtin_amdgcn_mfma_f32_32x32x16_bf16(av[kk][mf], bv[kk][0], acc[mf][0], 0, 0, 0);
          acc[mf][1] = __builtin_amdgcn_mfma_f32_32x32x16_bf16(av[kk][mf], bv[kk][1], acc[mf][1], 0, 0, 0);
        }
      }
      __builtin_amdgcn_s_setprio(0);
      __builtin_amdgcn_sched_barrier(0);
      BARRIER();
    }
    // ================= phase B (ks 2,3) =================
    {
      bf16x8 av[2][4], bv[2][2];
      #pragma unroll
      for (int kk = 0; kk < 2; ++kk) {
        const int bel = (((kk + 2) * 16 + kb) ^ bkey8);
        bv[kk][0] = *(const bf16x8*)(xb0 + bel);
        bv[kk][1] = *(const bf16x8*)(xb0 + 32 * 64 + bel);
        #pragma unroll
        for (int mf = 0; mf < 4; ++mf)
          av[kk][mf] = *(const bf16x8*)(wbase + mf * 2048 + ael[kk + 2]);
      }
      if (s >= 69) { WAITV(0); }            // tail: ensure final W tiles land
      else         { WAITV(4); }            // queue: W(s+1),W(s+2) -> W(s+1) landed
      BARRIER();
      LGKM0();
      __builtin_amdgcn_s_setprio(1);
      #pragma unroll
      for (int kk = 0; kk < 2; ++kk) {
        #pragma unroll
        for (int mf = 0; mf < 4; ++mf) {
          acc[mf][0] = __builtin_amdgcn_mfma_f32_32x32x16_bf16(av[kk][mf], bv[kk][0], acc[mf][0], 0, 0, 0);
          acc[mf][1] = __builtin_amdgcn_mfma_f32_32x32x16_bf16(av[kk][mf], bv[kk][1], acc[mf][1], 0, 0, 0);
        }
      }
      __builtin_amdgcn_s_setprio(0);
      __builtin_amdgcn_sched_barrier(0);
      BARRIER();
    }
    if (tap == 8 && chunk < 7) stage_x(chunk + 1);  // Xs reads all done past final barrier

    if (++tap == 9) { tap = 0; ++chunk; }
    if (++buf == 3) buf = 0;
  }

  // epilogue: out = acc * (demod*cs), NCHW
  const int y = r0 + wn;
  #pragma unroll
  for (int mf = 0; mf < 4; ++mf) {
    #pragma unroll
    for (int reg = 0; reg < 16; ++reg) {
      const int rowid = (reg & 3) + 8 * (reg >> 2) + 4 * laneK;
      const int oc = oc0 + 128 * wm + 32 * mf + rowid;
      const float sc = scale[b * OUT_CH + oc];
      float* op = out + (((size_t)(b * OUT_CH + oc) * HW + y) * HW) + ln31;
      op[0] = acc[mf][0][reg] * sc;
      op[32] = acc[mf][1][reg] * sc;
    }
  }
}

// ---------------- launcher ---------------------------------------------------------------
extern "C" void kernel_launch(void* const* d_in, const int* in_sizes, int n_in,
                              void* d_out, int out_size, void* d_ws, size_t ws_size,
                              hipStream_t stream) {
  const float* x      = (const float*)d_in[0];
  const float* style  = (const float*)d_in[1];
  const float* weight = (const float*)d_in[2];
  const float* modw   = (const float*)d_in[3];
  const float* modb   = (const float*)d_in[4];
  float* out = (float*)d_out;

  char* ws = (char*)d_ws;
  float*  s_buf = (float*)(ws + 0);
  float*  scale = (float*)(ws + 16384);
  float*  wsq   = (float*)(ws + 32768);
  __bf16* wb    = (__bf16*)(ws + 32768 + 1048576);
  __bf16* xg    = (__bf16*)(ws + 32768 + 1048576 + 9 * OUT_CH * IN_CH * 2);

  k_style<<<128, 256, 0, stream>>>(style, modw, modb, s_buf);
  k_wprep<<<1024, 256, 0, stream>>>(weight, wsq, wb);
  k_demod<<<512, 64, 0, stream>>>(s_buf, wsq, scale);
  k_xprep<<<BATCH * HW, 512, 0, stream>>>(x, s_buf, xg);
  k_conv<<<256, 512, 0, stream>>>(wb, xg, scale, out);
}